// Round 4
// baseline (4873.418 us; speedup 1.0000x reference)
//
#include <hip/hip_runtime.h>

#define FD 64          // feature dim
#define NBMAX 2560     // max bucket count (aff: ceil(150000/64)=2344)
#define CH 16384       // edges per block in count/scatter

// ---------------- utility ----------------

static __global__ void zero_int_kernel(int* __restrict__ p, int n) {
    int i = blockIdx.x * blockDim.x + threadIdx.x;
    if (i < n) p[i] = 0;
}

static inline unsigned gridFor(long long n, int block) {
    return (unsigned)((n + block - 1) / block);
}

// ---------------- bucket build: count -> scan -> clustered scatter ----------------

template <int BR>
static __global__ void bucket_count_kernel(const int* __restrict__ rows, int nnz, int nb,
                                           int* __restrict__ gcount) {
    __shared__ int h[NBMAX];
    long long c0 = (long long)blockIdx.x * CH;
    int cnt = (int)((nnz - c0) < CH ? (nnz - c0) : CH);
    for (int i = threadIdx.x; i < nb; i += blockDim.x) h[i] = 0;
    __syncthreads();
    for (int i = threadIdx.x; i < cnt; i += blockDim.x)
        atomicAdd(&h[rows[c0 + i] / BR], 1);
    __syncthreads();
    for (int i = threadIdx.x; i < nb; i += blockDim.x)
        if (h[i]) atomicAdd(&gcount[i], h[i]);
}

// single-block exclusive scan of nb (<= NBMAX) counts -> bptr, bcur; bptr[nb] = nnz
static __global__ void bucket_scan_kernel(const int* __restrict__ gcount, int nb, int nnz,
                                          int* __restrict__ bptr, int* __restrict__ bcur) {
    __shared__ int tsum[1024];
    int k = (nb + 1023) / 1024;
    int start = threadIdx.x * k;
    int s = 0;
    for (int i = 0; i < k; ++i) {
        int idx = start + i;
        if (idx < nb) s += gcount[idx];
    }
    tsum[threadIdx.x] = s;
    __syncthreads();
    for (int off = 1; off < 1024; off <<= 1) {
        int t = (threadIdx.x >= (unsigned)off) ? tsum[threadIdx.x - off] : 0;
        __syncthreads();
        tsum[threadIdx.x] += t;
        __syncthreads();
    }
    int run = tsum[threadIdx.x] - s;  // exclusive base for this thread's range
    for (int i = 0; i < k; ++i) {
        int idx = start + i;
        if (idx < nb) {
            bptr[idx] = run;
            bcur[idx] = run;
            run += gcount[idx];
        }
    }
    if (threadIdx.x == 0) bptr[nb] = nnz;
}

// LDS-binned clustered scatter: edges of same bucket from one block land contiguously.
// pack.x = (row % BR) << 24 | col ; pack.y = val bits
template <int BR>
static __global__ void bucket_scatter_kernel(const int* __restrict__ rows,
                                             const int* __restrict__ cols,
                                             const float* __restrict__ vals,
                                             int nnz, int nb,
                                             int* __restrict__ bcur,
                                             int2* __restrict__ epack) {
    __shared__ int h[NBMAX];
    __shared__ int base[NBMAX];
    long long c0 = (long long)blockIdx.x * CH;
    int cnt = (int)((nnz - c0) < CH ? (nnz - c0) : CH);
    for (int i = threadIdx.x; i < nb; i += blockDim.x) h[i] = 0;
    __syncthreads();
    for (int i = threadIdx.x; i < cnt; i += blockDim.x)
        atomicAdd(&h[rows[c0 + i] / BR], 1);
    __syncthreads();
    for (int i = threadIdx.x; i < nb; i += blockDim.x) {
        int c = h[i];
        base[i] = c ? atomicAdd(&bcur[i], c) : 0;
        h[i] = 0;
    }
    __syncthreads();
    for (int i = threadIdx.x; i < cnt; i += blockDim.x) {
        int r = rows[c0 + i];
        int b = r / BR;
        int rank = atomicAdd(&h[b], 1);
        int packed = ((r % BR) << 24) | cols[c0 + i];
        epack[base[b] + rank] = make_int2(packed, __float_as_int(vals[c0 + i]));
    }
}

// ---------------- bucket SpMM with LDS accumulation + fused epilogue ----------------
// One block per bucket of BR rows. Waves iterate bucket edges; lane d = dim d;
// accumulate into LDS via atomicAdd. Epilogue per row:
//   s = lds_row * scale
//   WRITE_NXT: nxt[r] = s
//   NORM: basev = (VIRT ? concat(fa,fb)[r] : accbuf[r]); res = basev + s/max(||s||,1e-12)
//         WRITE_ACC: accbuf[r] = res;  out_lo (r<out_split) / out_hi (r>=out_split) = res
template <int BR, bool VIRT, bool WRITE_NXT, bool NORM, bool WRITE_ACC>
static __global__ void spmm_bucket_kernel(const int* __restrict__ bptr,
                                          const int2* __restrict__ epack,
                                          const float* __restrict__ feats,
                                          const float* __restrict__ fa,
                                          const float* __restrict__ fb, int split,
                                          float* __restrict__ nxt,
                                          float* __restrict__ accbuf,
                                          float* __restrict__ out_lo,
                                          float* __restrict__ out_hi,
                                          int out_split, int n, float scale) {
    __shared__ float acc[BR * FD];
    int b = blockIdx.x;
    int d = threadIdx.x & 63;
    int wv = threadIdx.x >> 6;
    const int NW = blockDim.x >> 6;
    for (int i = threadIdx.x; i < BR * FD; i += blockDim.x) acc[i] = 0.0f;
    __syncthreads();
    int beg = bptr[b], end = bptr[b + 1];
    for (int e = beg + wv; e < end; e += NW) {
        int2 p = epack[e];
        int rl = ((unsigned)p.x) >> 24;
        int c = p.x & 0xFFFFFF;
        float v = __int_as_float(p.y);
        float f;
        if (VIRT)
            f = (c < split) ? fa[(long long)c * FD + d]
                            : fb[(long long)(c - split) * FD + d];
        else
            f = feats[(long long)c * FD + d];
        atomicAdd(&acc[rl * FD + d], v * f);
    }
    __syncthreads();
    for (int i = wv; i < BR; i += NW) {
        int r = b * BR + i;
        if (r >= n) break;
        float s = acc[i * FD + d] * scale;
        long long idx = (long long)r * FD + d;
        if (WRITE_NXT) nxt[idx] = s;
        if (NORM) {
            float sq = s * s;
            #pragma unroll
            for (int off = 32; off > 0; off >>= 1) sq += __shfl_xor(sq, off);
            float basev = VIRT ? ((r < split) ? fa[(long long)r * FD + d]
                                              : fb[(long long)(r - split) * FD + d])
                               : accbuf[idx];
            float res = basev + s / fmaxf(sqrtf(sq), 1e-12f);
            if (WRITE_ACC) accbuf[idx] = res;
            if (out_lo && r < out_split) out_lo[(long long)r * FD + d] = res;
            if (out_hi && r >= out_split) out_hi[(long long)(r - out_split) * FD + d] = res;
        }
    }
}

// ---------------- build driver ----------------

template <int BR>
static void build_buckets(const int* rows, const int* cols, const float* vals,
                          int nnz, int nb,
                          int* gcount, int* bptr, int* bcur, int2* epack,
                          hipStream_t stream) {
    unsigned gb = gridFor(nnz, CH);
    zero_int_kernel<<<gridFor(nb, 256), 256, 0, stream>>>(gcount, nb);
    bucket_count_kernel<BR><<<gb, 256, 0, stream>>>(rows, nnz, nb, gcount);
    bucket_scan_kernel<<<1, 1024, 0, stream>>>(gcount, nb, nnz, bptr, bcur);
    bucket_scatter_kernel<BR><<<gb, 256, 0, stream>>>(rows, cols, vals, nnz, nb, bcur, epack);
}

extern "C" void kernel_launch(void* const* d_in, const int* in_sizes, int n_in,
                              void* d_out, int out_size, void* d_ws, size_t ws_size,
                              hipStream_t stream) {
    const float* users   = (const float*)d_in[0];
    const float* items   = (const float*)d_in[1];
    const float* bundles = (const float*)d_in[2];
    const int*   aff_rows = (const int*)d_in[3];
    const int*   aff_cols = (const int*)d_in[4];
    const float* aff_vals = (const float*)d_in[5];
    const int*   hist_rows = (const int*)d_in[6];
    const int*   hist_cols = (const int*)d_in[7];
    const float* hist_vals = (const float*)d_in[8];
    const int*   agg_rows = (const int*)d_in[9];
    const int*   agg_cols = (const int*)d_in[10];
    const float* agg_vals = (const float*)d_in[11];

    const int U = in_sizes[0] / FD;
    const int I = in_sizes[1] / FD;
    const int B = in_sizes[2] / FD;
    const int nnz_aff  = in_sizes[3];
    const int nnz_hist = in_sizes[6];
    const int nnz_agg  = in_sizes[9];
    const int n1 = U + I;
    const int n2 = U + B;
    int nnz_max = nnz_aff > nnz_hist ? nnz_aff : nnz_hist;
    if (nnz_agg > nnz_max) nnz_max = nnz_agg;

    float* out = (float*)d_out;

    const long long n1e = (long long)n1 * FD;
    const long long Ue  = (long long)U * FD;
    const long long Be  = (long long)B * FD;

    // workspace layout
    float* nxt = (float*)d_ws;
    float* acc = nxt + n1e;
    int2*  epack = (int2*)(acc + n1e);            // nnz_max int2
    int*   bptr  = (int*)(epack + nnz_max);       // NBMAX+1
    int*   bcur  = bptr + (NBMAX + 1);            // NBMAX
    int*   gcount = bcur + NBMAX;                 // NBMAX

    const int nbA = (n1 + 63) / 64;
    const int nbH = (n2 + 63) / 64;
    const int nbG = (B + 31) / 32;

    // ---------------- aff propagate over (U+I) nodes ----------------
    build_buckets<64>(aff_rows, aff_cols, aff_vals, nnz_aff, nbA,
                      gcount, bptr, bcur, epack, stream);
    // L1: nxt = spmm(concat(users,items))/2 ; acc = concat + l2norm(nxt)
    spmm_bucket_kernel<64, true, true, true, true><<<nbA, 256, 0, stream>>>(
        bptr, epack, nullptr, users, items, U,
        nxt, acc, nullptr, nullptr, 0, n1, 0.5f);
    // L2: res = acc + l2norm(spmm(nxt)/3); keep in acc (agg needs items part); rows<U -> aff_users
    spmm_bucket_kernel<64, false, false, true, true><<<nbA, 256, 0, stream>>>(
        bptr, epack, nxt, nullptr, nullptr, 0,
        nullptr, acc, out, nullptr, U, n1, 1.0f / 3.0f);

    // ---------------- aff_bundles = agg_spmm(aff items) -> out[2U : 2U+B] ----------------
    build_buckets<32>(agg_rows, agg_cols, agg_vals, nnz_agg, nbG,
                      gcount, bptr, bcur, epack, stream);
    spmm_bucket_kernel<32, false, true, false, false><<<nbG, 256, 0, stream>>>(
        bptr, epack, acc + Ue, nullptr, nullptr, 0,
        out + 2 * Ue, nullptr, nullptr, nullptr, 0, B, 1.0f);

    // ---------------- hist propagate over (U+B) nodes ----------------
    build_buckets<64>(hist_rows, hist_cols, hist_vals, nnz_hist, nbH,
                      gcount, bptr, bcur, epack, stream);
    spmm_bucket_kernel<64, true, true, true, true><<<nbH, 256, 0, stream>>>(
        bptr, epack, nullptr, users, bundles, U,
        nxt, acc, nullptr, nullptr, 0, n2, 0.5f);
    // L2: res = acc + l2norm(spmm/3); rows<U -> hist_users, rows>=U -> hist_bundles
    spmm_bucket_kernel<64, false, false, true, false><<<nbH, 256, 0, stream>>>(
        bptr, epack, nxt, nullptr, nullptr, 0,
        nullptr, acc, out + Ue, out + 2 * Ue + Be, U, n2, 1.0f / 3.0f);
}

// Round 5
// 786.388 us; speedup vs baseline: 6.1972x; 6.1972x over previous
//
#include <hip/hip_runtime.h>

#define FD 64          // feature dim
#define BR 64          // rows per bucket
#define NBMAX 2560     // max bucket count (aff: ceil(150016/64)=2344)
#define CH 8192        // edges per block in count/scatter

// ---------------- utility ----------------

static __global__ void zero_int_kernel(int* __restrict__ p, int n) {
    int i = blockIdx.x * blockDim.x + threadIdx.x;
    if (i < n) p[i] = 0;
}

static inline unsigned gridFor(long long n, int block) {
    return (unsigned)((n + block - 1) / block);
}

// ---------------- bucket build: count -> scan -> clustered scatter -> local sort ----------------

static __global__ void bucket_count_kernel(const int* __restrict__ rows, int nnz, int nb,
                                           int* __restrict__ gcount) {
    __shared__ int h[NBMAX];
    long long c0 = (long long)blockIdx.x * CH;
    int cnt = (int)((nnz - c0) < CH ? (nnz - c0) : CH);
    for (int i = threadIdx.x; i < nb; i += blockDim.x) h[i] = 0;
    __syncthreads();
    for (int i = threadIdx.x; i < cnt; i += blockDim.x)
        atomicAdd(&h[rows[c0 + i] / BR], 1);
    __syncthreads();
    for (int i = threadIdx.x; i < nb; i += blockDim.x)
        if (h[i]) atomicAdd(&gcount[i], h[i]);
}

// single-block exclusive scan of nb (<= NBMAX) counts -> bptr, bcur; bptr[nb] = nnz
static __global__ void bucket_scan_kernel(const int* __restrict__ gcount, int nb, int nnz,
                                          int* __restrict__ bptr, int* __restrict__ bcur) {
    __shared__ int tsum[1024];
    int k = (nb + 1023) / 1024;
    int start = threadIdx.x * k;
    int s = 0;
    for (int i = 0; i < k; ++i) {
        int idx = start + i;
        if (idx < nb) s += gcount[idx];
    }
    tsum[threadIdx.x] = s;
    __syncthreads();
    for (int off = 1; off < 1024; off <<= 1) {
        int t = (threadIdx.x >= (unsigned)off) ? tsum[threadIdx.x - off] : 0;
        __syncthreads();
        tsum[threadIdx.x] += t;
        __syncthreads();
    }
    int run = tsum[threadIdx.x] - s;  // exclusive base for this thread's range
    for (int i = 0; i < k; ++i) {
        int idx = start + i;
        if (idx < nb) {
            bptr[idx] = run;
            bcur[idx] = run;
            run += gcount[idx];
        }
    }
    if (threadIdx.x == 0) bptr[nb] = nnz;
}

// LDS-binned clustered scatter: edges of same bucket from one block land contiguously.
// pack.x = (row % BR) << 24 | col ; pack.y = val bits
static __global__ void bucket_scatter_kernel(const int* __restrict__ rows,
                                             const int* __restrict__ cols,
                                             const float* __restrict__ vals,
                                             int nnz, int nb,
                                             int* __restrict__ bcur,
                                             int2* __restrict__ etmp) {
    __shared__ int h[NBMAX];
    __shared__ int base[NBMAX];
    long long c0 = (long long)blockIdx.x * CH;
    int cnt = (int)((nnz - c0) < CH ? (nnz - c0) : CH);
    for (int i = threadIdx.x; i < nb; i += blockDim.x) h[i] = 0;
    __syncthreads();
    for (int i = threadIdx.x; i < cnt; i += blockDim.x)
        atomicAdd(&h[rows[c0 + i] / BR], 1);
    __syncthreads();
    for (int i = threadIdx.x; i < nb; i += blockDim.x) {
        int c = h[i];
        base[i] = c ? atomicAdd(&bcur[i], c) : 0;
        h[i] = 0;
    }
    __syncthreads();
    for (int i = threadIdx.x; i < cnt; i += blockDim.x) {
        int r = rows[c0 + i];
        int b = r / BR;
        int rank = atomicAdd(&h[b], 1);
        int packed = ((r % BR) << 24) | cols[c0 + i];
        etmp[base[b] + rank] = make_int2(packed, __float_as_int(vals[c0 + i]));
    }
}

// per-bucket counting sort: bucket-sorted etmp -> row-sorted epack (+ row_ptr)
// all reads/writes within the bucket's contiguous region
static __global__ void bucket_local_sort_kernel(const int* __restrict__ bptr,
                                                const int2* __restrict__ etmp,
                                                int2* __restrict__ epack,
                                                int* __restrict__ row_ptr,
                                                int n, int nnz) {
    __shared__ int cnt[BR];
    __shared__ int startS[BR];
    int b = blockIdx.x;
    int beg = bptr[b], end = bptr[b + 1];
    if (threadIdx.x < BR) cnt[threadIdx.x] = 0;
    __syncthreads();
    for (int e = beg + threadIdx.x; e < end; e += blockDim.x)
        atomicAdd(&cnt[((unsigned)etmp[e].x) >> 24], 1);
    __syncthreads();
    if (threadIdx.x < BR) {
        int v = cnt[threadIdx.x];
        int s = v;
        #pragma unroll
        for (int off = 1; off < BR; off <<= 1) {
            int t = __shfl_up(s, off);
            if ((int)(threadIdx.x & 63) >= off) s += t;
        }
        startS[threadIdx.x] = s - v;
        cnt[threadIdx.x] = 0;
        int r = b * BR + threadIdx.x;
        if (r < n) row_ptr[r] = beg + s - v;
    }
    __syncthreads();
    for (int e = beg + threadIdx.x; e < end; e += blockDim.x) {
        int2 p = etmp[e];
        int rl = ((unsigned)p.x) >> 24;
        int rank = atomicAdd(&cnt[rl], 1);
        epack[beg + startS[rl] + rank] = make_int2(p.x & 0xFFFFFF, p.y);
    }
    if (b == 0 && threadIdx.x == 0) row_ptr[n] = nnz;
}

static void build_csr(const int* rows, const int* cols, const float* vals,
                      int nnz, int n, int nb,
                      int* gcount, int* bptr, int* bcur, int2* etmp, int2* epack,
                      int* row_ptr, hipStream_t stream) {
    unsigned gb = gridFor(nnz, CH);
    zero_int_kernel<<<gridFor(nb, 256), 256, 0, stream>>>(gcount, nb);
    bucket_count_kernel<<<gb, 256, 0, stream>>>(rows, nnz, nb, gcount);
    bucket_scan_kernel<<<1, 1024, 0, stream>>>(gcount, nb, nnz, bptr, bcur);
    bucket_scatter_kernel<<<gb, 256, 0, stream>>>(rows, cols, vals, nnz, nb, bcur, etmp);
    bucket_local_sort_kernel<<<nb, 256, 0, stream>>>(bptr, etmp, epack, row_ptr, n, nnz);
}

// ---------------- fused gather SpMM (+ optional l2norm accumulate) ----------------
// One 64-lane wave per row; lane d = feature dim d.
// feats(c) = VIRT ? (c<split ? fa[c] : fb[c-split]) : feats[c]
// s = scale * sum_e val[e] * feats(col[e])[d]
// WRITE_OUT: outbuf[idx] = s
// NORM: basev = (VIRT ? feats(r) : accbuf[idx]); res = basev + s/max(||s_row||,1e-12)
//   WRITE_ACC: accbuf[idx] = res
//   out_lo (r < out_split) / out_hi (r >= out_split) get res
template <bool VIRT, bool WRITE_OUT, bool NORM, bool WRITE_ACC>
static __global__ void spmm_gather_kernel(const int* __restrict__ row_ptr,
                                          const int2* __restrict__ epack,
                                          const float* __restrict__ feats,
                                          const float* __restrict__ fa,
                                          const float* __restrict__ fb, int split,
                                          float* __restrict__ outbuf,
                                          float* __restrict__ accbuf,
                                          float* __restrict__ out_lo,
                                          float* __restrict__ out_hi,
                                          int out_split, int n, float scale) {
    long long t = (long long)blockIdx.x * blockDim.x + threadIdx.x;
    int r = (int)(t >> 6);
    if (r >= n) return;
    int d = (int)(t & 63);
    int beg = row_ptr[r];
    int end = row_ptr[r + 1];
    float acc = 0.0f;
    int e = beg;
    for (; e + 3 < end; e += 4) {
        int2 p0 = epack[e];
        int2 p1 = epack[e + 1];
        int2 p2 = epack[e + 2];
        int2 p3 = epack[e + 3];
        float f0, f1, f2, f3;
        if (VIRT) {
            f0 = (p0.x < split) ? fa[(long long)p0.x * FD + d] : fb[(long long)(p0.x - split) * FD + d];
            f1 = (p1.x < split) ? fa[(long long)p1.x * FD + d] : fb[(long long)(p1.x - split) * FD + d];
            f2 = (p2.x < split) ? fa[(long long)p2.x * FD + d] : fb[(long long)(p2.x - split) * FD + d];
            f3 = (p3.x < split) ? fa[(long long)p3.x * FD + d] : fb[(long long)(p3.x - split) * FD + d];
        } else {
            f0 = feats[(long long)p0.x * FD + d];
            f1 = feats[(long long)p1.x * FD + d];
            f2 = feats[(long long)p2.x * FD + d];
            f3 = feats[(long long)p3.x * FD + d];
        }
        acc += __int_as_float(p0.y) * f0;
        acc += __int_as_float(p1.y) * f1;
        acc += __int_as_float(p2.y) * f2;
        acc += __int_as_float(p3.y) * f3;
    }
    for (; e < end; ++e) {
        int2 p = epack[e];
        float f;
        if (VIRT)
            f = (p.x < split) ? fa[(long long)p.x * FD + d] : fb[(long long)(p.x - split) * FD + d];
        else
            f = feats[(long long)p.x * FD + d];
        acc += __int_as_float(p.y) * f;
    }
    float s = acc * scale;
    long long idx = (long long)r * FD + d;
    if (WRITE_OUT) outbuf[idx] = s;
    if (NORM) {
        float sq = s * s;
        #pragma unroll
        for (int off = 32; off > 0; off >>= 1) sq += __shfl_xor(sq, off);
        float basev;
        if (VIRT)
            basev = (r < split) ? fa[(long long)r * FD + d] : fb[(long long)(r - split) * FD + d];
        else
            basev = accbuf[idx];
        float res = basev + s / fmaxf(sqrtf(sq), 1e-12f);
        if (WRITE_ACC) accbuf[idx] = res;
        if (out_lo && r < out_split) out_lo[(long long)r * FD + d] = res;
        if (out_hi && r >= out_split) out_hi[(long long)(r - out_split) * FD + d] = res;
    }
}

extern "C" void kernel_launch(void* const* d_in, const int* in_sizes, int n_in,
                              void* d_out, int out_size, void* d_ws, size_t ws_size,
                              hipStream_t stream) {
    const float* users   = (const float*)d_in[0];
    const float* items   = (const float*)d_in[1];
    const float* bundles = (const float*)d_in[2];
    const int*   aff_rows = (const int*)d_in[3];
    const int*   aff_cols = (const int*)d_in[4];
    const float* aff_vals = (const float*)d_in[5];
    const int*   hist_rows = (const int*)d_in[6];
    const int*   hist_cols = (const int*)d_in[7];
    const float* hist_vals = (const float*)d_in[8];
    const int*   agg_rows = (const int*)d_in[9];
    const int*   agg_cols = (const int*)d_in[10];
    const float* agg_vals = (const float*)d_in[11];

    const int U = in_sizes[0] / FD;
    const int I = in_sizes[1] / FD;
    const int B = in_sizes[2] / FD;
    const int nnz_aff  = in_sizes[3];
    const int nnz_hist = in_sizes[6];
    const int nnz_agg  = in_sizes[9];
    const int n1 = U + I;
    const int n2 = U + B;
    int nnz_max = nnz_aff > nnz_hist ? nnz_aff : nnz_hist;
    if (nnz_agg > nnz_max) nnz_max = nnz_agg;

    float* out = (float*)d_out;

    const long long n1e = (long long)n1 * FD;
    const long long n2e = (long long)n2 * FD;
    const long long Ue  = (long long)U * FD;
    const long long Be  = (long long)B * FD;

    // workspace layout
    float* nxt = (float*)d_ws;                    // n1e
    float* acc = nxt + n1e;                       // n1e
    int2*  etmp  = (int2*)(acc + n1e);            // nnz_max
    int2*  epack = etmp + nnz_max;                // nnz_max
    int*   bptr  = (int*)(epack + nnz_max);       // NBMAX+1
    int*   bcur  = bptr + (NBMAX + 1);            // NBMAX
    int*   gcount = bcur + NBMAX;                 // NBMAX
    int*   row_ptr = gcount + NBMAX;              // n1+1

    const int BLK = 256;
    const int nbA = (n1 + BR - 1) / BR;
    const int nbH = (n2 + BR - 1) / BR;
    const int nbG = (B + BR - 1) / BR;

    // ---------------- aff propagate over (U+I) nodes ----------------
    build_csr(aff_rows, aff_cols, aff_vals, nnz_aff, n1, nbA,
              gcount, bptr, bcur, etmp, epack, row_ptr, stream);
    // L1: nxt = spmm(concat(users,items))/2 ; acc = concat + l2norm(nxt)
    spmm_gather_kernel<true, true, true, true><<<gridFor(n1e, BLK), BLK, 0, stream>>>(
        row_ptr, epack, nullptr, users, items, U,
        nxt, acc, nullptr, nullptr, 0, n1, 0.5f);
    // L2: acc += l2norm(spmm(nxt)/3); rows<U also -> out (aff_users)
    spmm_gather_kernel<false, false, true, true><<<gridFor(n1e, BLK), BLK, 0, stream>>>(
        row_ptr, epack, nxt, nullptr, nullptr, 0,
        nullptr, acc, out, nullptr, U, n1, 1.0f / 3.0f);

    // ---------------- aff_bundles = agg_spmm(aff items) -> out[2U : 2U+B] ----------------
    build_csr(agg_rows, agg_cols, agg_vals, nnz_agg, B, nbG,
              gcount, bptr, bcur, etmp, epack, row_ptr, stream);
    spmm_gather_kernel<false, true, false, false><<<gridFor(Be, BLK), BLK, 0, stream>>>(
        row_ptr, epack, acc + Ue, nullptr, nullptr, 0,
        out + 2 * Ue, nullptr, nullptr, nullptr, 0, B, 1.0f);

    // ---------------- hist propagate over (U+B) nodes ----------------
    build_csr(hist_rows, hist_cols, hist_vals, nnz_hist, n2, nbH,
              gcount, bptr, bcur, etmp, epack, row_ptr, stream);
    spmm_gather_kernel<true, true, true, true><<<gridFor(n2e, BLK), BLK, 0, stream>>>(
        row_ptr, epack, nullptr, users, bundles, U,
        nxt, acc, nullptr, nullptr, 0, n2, 0.5f);
    // L2: res = acc + l2norm(spmm/3); rows<U -> hist_users, rows>=U -> hist_bundles
    spmm_gather_kernel<false, false, true, false><<<gridFor(n2e, BLK), BLK, 0, stream>>>(
        row_ptr, epack, nxt, nullptr, nullptr, 0,
        nullptr, acc, out + Ue, out + 2 * Ue + Be, U, n2, 1.0f / 3.0f);
}

// Round 6
// 696.109 us; speedup vs baseline: 7.0009x; 1.1297x over previous
//
#include <hip/hip_runtime.h>

#define FD 64          // feature dim
#define BR 64          // rows per bucket
#define NBMAX 2560     // max bucket count (aff: ceil(150016/64)=2344)
#define CH 8192        // edges per block in count/scatter

// ---------------- utility ----------------

static __global__ void zero_int_kernel(int* __restrict__ p, int n) {
    int i = blockIdx.x * blockDim.x + threadIdx.x;
    if (i < n) p[i] = 0;
}

static inline unsigned gridFor(long long n, int block) {
    return (unsigned)((n + block - 1) / block);
}

// ---------------- bucket build: count -> scan -> clustered scatter -> local sort ----------------

static __global__ void bucket_count_kernel(const int* __restrict__ rows, int nnz, int nb,
                                           int* __restrict__ gcount) {
    __shared__ int h[NBMAX];
    long long c0 = (long long)blockIdx.x * CH;
    int cnt = (int)((nnz - c0) < CH ? (nnz - c0) : CH);
    for (int i = threadIdx.x; i < nb; i += blockDim.x) h[i] = 0;
    __syncthreads();
    for (int i = threadIdx.x; i < cnt; i += blockDim.x)
        atomicAdd(&h[rows[c0 + i] / BR], 1);
    __syncthreads();
    for (int i = threadIdx.x; i < nb; i += blockDim.x)
        if (h[i]) atomicAdd(&gcount[i], h[i]);
}

// single-block exclusive scan of nb (<= NBMAX) counts -> bptr, bcur; bptr[nb] = nnz
static __global__ void bucket_scan_kernel(const int* __restrict__ gcount, int nb, int nnz,
                                          int* __restrict__ bptr, int* __restrict__ bcur) {
    __shared__ int tsum[1024];
    int k = (nb + 1023) / 1024;
    int start = threadIdx.x * k;
    int s = 0;
    for (int i = 0; i < k; ++i) {
        int idx = start + i;
        if (idx < nb) s += gcount[idx];
    }
    tsum[threadIdx.x] = s;
    __syncthreads();
    for (int off = 1; off < 1024; off <<= 1) {
        int t = (threadIdx.x >= (unsigned)off) ? tsum[threadIdx.x - off] : 0;
        __syncthreads();
        tsum[threadIdx.x] += t;
        __syncthreads();
    }
    int run = tsum[threadIdx.x] - s;  // exclusive base for this thread's range
    for (int i = 0; i < k; ++i) {
        int idx = start + i;
        if (idx < nb) {
            bptr[idx] = run;
            bcur[idx] = run;
            run += gcount[idx];
        }
    }
    if (threadIdx.x == 0) bptr[nb] = nnz;
}

// LDS-binned clustered scatter: edges of same bucket from one block land contiguously.
// pack.x = (row % BR) << 24 | col ; pack.y = val bits
static __global__ void bucket_scatter_kernel(const int* __restrict__ rows,
                                             const int* __restrict__ cols,
                                             const float* __restrict__ vals,
                                             int nnz, int nb,
                                             int* __restrict__ bcur,
                                             int2* __restrict__ etmp) {
    __shared__ int h[NBMAX];
    __shared__ int base[NBMAX];
    long long c0 = (long long)blockIdx.x * CH;
    int cnt = (int)((nnz - c0) < CH ? (nnz - c0) : CH);
    for (int i = threadIdx.x; i < nb; i += blockDim.x) h[i] = 0;
    __syncthreads();
    for (int i = threadIdx.x; i < cnt; i += blockDim.x)
        atomicAdd(&h[rows[c0 + i] / BR], 1);
    __syncthreads();
    for (int i = threadIdx.x; i < nb; i += blockDim.x) {
        int c = h[i];
        base[i] = c ? atomicAdd(&bcur[i], c) : 0;
        h[i] = 0;
    }
    __syncthreads();
    for (int i = threadIdx.x; i < cnt; i += blockDim.x) {
        int r = rows[c0 + i];
        int b = r / BR;
        int rank = atomicAdd(&h[b], 1);
        int packed = ((r % BR) << 24) | cols[c0 + i];
        etmp[base[b] + rank] = make_int2(packed, __float_as_int(vals[c0 + i]));
    }
}

// per-bucket counting sort: bucket-sorted etmp -> row-sorted epack (+ row_ptr)
static __global__ void bucket_local_sort_kernel(const int* __restrict__ bptr,
                                                const int2* __restrict__ etmp,
                                                int2* __restrict__ epack,
                                                int* __restrict__ row_ptr,
                                                int n, int nnz) {
    __shared__ int cnt[BR];
    __shared__ int startS[BR];
    int b = blockIdx.x;
    int beg = bptr[b], end = bptr[b + 1];
    if (threadIdx.x < BR) cnt[threadIdx.x] = 0;
    __syncthreads();
    for (int e = beg + threadIdx.x; e < end; e += blockDim.x)
        atomicAdd(&cnt[((unsigned)etmp[e].x) >> 24], 1);
    __syncthreads();
    if (threadIdx.x < BR) {
        int v = cnt[threadIdx.x];
        int s = v;
        #pragma unroll
        for (int off = 1; off < BR; off <<= 1) {
            int t = __shfl_up(s, off);
            if ((int)(threadIdx.x & 63) >= off) s += t;
        }
        startS[threadIdx.x] = s - v;
        cnt[threadIdx.x] = 0;
        int r = b * BR + threadIdx.x;
        if (r < n) row_ptr[r] = beg + s - v;
    }
    __syncthreads();
    for (int e = beg + threadIdx.x; e < end; e += blockDim.x) {
        int2 p = etmp[e];
        int rl = ((unsigned)p.x) >> 24;
        int rank = atomicAdd(&cnt[rl], 1);
        epack[beg + startS[rl] + rank] = make_int2(p.x & 0xFFFFFF, p.y);
    }
    if (b == 0 && threadIdx.x == 0) row_ptr[n] = nnz;
}

static void build_csr(const int* rows, const int* cols, const float* vals,
                      int nnz, int n, int nb,
                      int* gcount, int* bptr, int* bcur, int2* etmp, int2* epack,
                      int* row_ptr, hipStream_t stream) {
    unsigned gb = gridFor(nnz, CH);
    zero_int_kernel<<<gridFor(nb, 256), 256, 0, stream>>>(gcount, nb);
    bucket_count_kernel<<<gb, 256, 0, stream>>>(rows, nnz, nb, gcount);
    bucket_scan_kernel<<<1, 1024, 0, stream>>>(gcount, nb, nnz, bptr, bcur);
    bucket_scatter_kernel<<<gb, 256, 0, stream>>>(rows, cols, vals, nnz, nb, bcur, etmp);
    bucket_local_sort_kernel<<<nb, 256, 0, stream>>>(bptr, etmp, epack, row_ptr, n, nnz);
}

// ---------------- fused gather SpMM, 16 lanes/row x float4 ----------------
// Subgroup of 16 lanes per row; lane l holds dims [4l, 4l+4).
// table(c) = VIRT ? (c<split ? fa4[c*16+l] : fb4[(c-split)*16+l]) : feats4[c*16+l]
// s = scale * sum_e val[e] * table(col[e])
// WRITE_OUT: outbuf4[r*16+l] = s
// NORM: basev = (VIRT ? table(r) : accbuf4[r*16+l]); res = basev + s/max(||s_row||,1e-12)
//   WRITE_ACC: accbuf4 = res;  out_lo (r<out_split) / out_hi (r>=out_split) = res
template <bool VIRT, bool WRITE_OUT, bool NORM, bool WRITE_ACC>
static __global__ void spmm_gather4_kernel(const int* __restrict__ row_ptr,
                                           const int2* __restrict__ epack,
                                           const float4* __restrict__ feats4,
                                           const float4* __restrict__ fa4,
                                           const float4* __restrict__ fb4, int split,
                                           float4* __restrict__ outbuf4,
                                           float4* __restrict__ accbuf4,
                                           float4* __restrict__ out_lo4,
                                           float4* __restrict__ out_hi4,
                                           int out_split, int n, float scale) {
    long long t = (long long)blockIdx.x * blockDim.x + threadIdx.x;
    int r = (int)(t >> 4);
    if (r >= n) return;
    int l = (int)(t & 15);
    const float4* fbm4 = VIRT ? (fb4 - (long long)split * 16) : nullptr;
    int beg = row_ptr[r];
    int end = row_ptr[r + 1];
    float4 acc = make_float4(0.f, 0.f, 0.f, 0.f);
    int e = beg;
    for (; e + 1 < end; e += 2) {
        int2 p0 = epack[e];
        int2 p1 = epack[e + 1];
        const float4* b0;
        const float4* b1;
        if (VIRT) {
            b0 = (p0.x < split) ? fa4 : fbm4;
            b1 = (p1.x < split) ? fa4 : fbm4;
        } else {
            b0 = feats4;
            b1 = feats4;
        }
        float4 f0 = b0[((long long)p0.x << 4) + l];
        float4 f1 = b1[((long long)p1.x << 4) + l];
        float v0 = __int_as_float(p0.y);
        float v1 = __int_as_float(p1.y);
        acc.x += v0 * f0.x; acc.y += v0 * f0.y; acc.z += v0 * f0.z; acc.w += v0 * f0.w;
        acc.x += v1 * f1.x; acc.y += v1 * f1.y; acc.z += v1 * f1.z; acc.w += v1 * f1.w;
    }
    if (e < end) {
        int2 p = epack[e];
        const float4* b = VIRT ? ((p.x < split) ? fa4 : fbm4) : feats4;
        float4 f = b[((long long)p.x << 4) + l];
        float v = __int_as_float(p.y);
        acc.x += v * f.x; acc.y += v * f.y; acc.z += v * f.z; acc.w += v * f.w;
    }
    float4 s;
    s.x = acc.x * scale; s.y = acc.y * scale; s.z = acc.z * scale; s.w = acc.w * scale;
    long long idx = ((long long)r << 4) + l;
    if (WRITE_OUT) outbuf4[idx] = s;
    if (NORM) {
        float sq = s.x * s.x + s.y * s.y + s.z * s.z + s.w * s.w;
        #pragma unroll
        for (int off = 8; off > 0; off >>= 1) sq += __shfl_xor(sq, off);
        float inv = 1.0f / fmaxf(sqrtf(sq), 1e-12f);
        float4 basev;
        if (VIRT)
            basev = (r < split) ? fa4[idx] : fbm4[idx];
        else
            basev = accbuf4[idx];
        float4 res;
        res.x = basev.x + s.x * inv;
        res.y = basev.y + s.y * inv;
        res.z = basev.z + s.z * inv;
        res.w = basev.w + s.w * inv;
        if (WRITE_ACC) accbuf4[idx] = res;
        if (out_lo4 && r < out_split) out_lo4[idx] = res;
        if (out_hi4 && r >= out_split) out_hi4[((long long)(r - out_split) << 4) + l] = res;
    }
}

extern "C" void kernel_launch(void* const* d_in, const int* in_sizes, int n_in,
                              void* d_out, int out_size, void* d_ws, size_t ws_size,
                              hipStream_t stream) {
    const float* users   = (const float*)d_in[0];
    const float* items   = (const float*)d_in[1];
    const float* bundles = (const float*)d_in[2];
    const int*   aff_rows = (const int*)d_in[3];
    const int*   aff_cols = (const int*)d_in[4];
    const float* aff_vals = (const float*)d_in[5];
    const int*   hist_rows = (const int*)d_in[6];
    const int*   hist_cols = (const int*)d_in[7];
    const float* hist_vals = (const float*)d_in[8];
    const int*   agg_rows = (const int*)d_in[9];
    const int*   agg_cols = (const int*)d_in[10];
    const float* agg_vals = (const float*)d_in[11];

    const int U = in_sizes[0] / FD;
    const int I = in_sizes[1] / FD;
    const int B = in_sizes[2] / FD;
    const int nnz_aff  = in_sizes[3];
    const int nnz_hist = in_sizes[6];
    const int nnz_agg  = in_sizes[9];
    const int n1 = U + I;
    const int n2 = U + B;
    int nnz_max = nnz_aff > nnz_hist ? nnz_aff : nnz_hist;
    if (nnz_agg > nnz_max) nnz_max = nnz_agg;

    float* out = (float*)d_out;

    const long long n1e = (long long)n1 * FD;
    const long long Ue  = (long long)U * FD;
    const long long Be  = (long long)B * FD;

    // workspace layout (same footprint as round 5)
    float* nxt = (float*)d_ws;                    // n1e
    float* acc = nxt + n1e;                       // n1e
    int2*  etmp  = (int2*)(acc + n1e);            // nnz_max
    int2*  epack = etmp + nnz_max;                // nnz_max
    int*   bptr  = (int*)(epack + nnz_max);       // NBMAX+1
    int*   bcur  = bptr + (NBMAX + 1);            // NBMAX
    int*   gcount = bcur + NBMAX;                 // NBMAX
    int*   row_ptr = gcount + NBMAX;              // n1+1

    const int BLK = 256;
    const int nbA = (n1 + BR - 1) / BR;
    const int nbH = (n2 + BR - 1) / BR;
    const int nbG = (B + BR - 1) / BR;

    const float4* users4   = (const float4*)users;
    const float4* items4   = (const float4*)items;
    const float4* bundles4 = (const float4*)bundles;
    float4* nxt4 = (float4*)nxt;
    float4* acc4 = (float4*)acc;
    float4* out4 = (float4*)out;

    // thread counts: 16 threads per row
    const long long tA = (long long)n1 * 16;
    const long long tH = (long long)n2 * 16;
    const long long tG = (long long)B * 16;

    // ---------------- aff propagate over (U+I) nodes ----------------
    build_csr(aff_rows, aff_cols, aff_vals, nnz_aff, n1, nbA,
              gcount, bptr, bcur, etmp, epack, row_ptr, stream);
    // L1: nxt = spmm(concat(users,items))/2 ; acc = concat + l2norm(nxt)
    spmm_gather4_kernel<true, true, true, true><<<gridFor(tA, BLK), BLK, 0, stream>>>(
        row_ptr, epack, nullptr, users4, items4, U,
        nxt4, acc4, nullptr, nullptr, 0, n1, 0.5f);
    // L2: acc += l2norm(spmm(nxt)/3); rows<U also -> out (aff_users)
    spmm_gather4_kernel<false, false, true, true><<<gridFor(tA, BLK), BLK, 0, stream>>>(
        row_ptr, epack, nxt4, nullptr, nullptr, 0,
        nullptr, acc4, out4, nullptr, U, n1, 1.0f / 3.0f);

    // ---------------- aff_bundles = agg_spmm(aff items) -> out[2U : 2U+B] ----------------
    build_csr(agg_rows, agg_cols, agg_vals, nnz_agg, B, nbG,
              gcount, bptr, bcur, etmp, epack, row_ptr, stream);
    spmm_gather4_kernel<false, true, false, false><<<gridFor(tG, BLK), BLK, 0, stream>>>(
        row_ptr, epack, (const float4*)(acc + Ue), nullptr, nullptr, 0,
        (float4*)(out + 2 * Ue), nullptr, nullptr, nullptr, 0, B, 1.0f);

    // ---------------- hist propagate over (U+B) nodes ----------------
    build_csr(hist_rows, hist_cols, hist_vals, nnz_hist, n2, nbH,
              gcount, bptr, bcur, etmp, epack, row_ptr, stream);
    spmm_gather4_kernel<true, true, true, true><<<gridFor(tH, BLK), BLK, 0, stream>>>(
        row_ptr, epack, nullptr, users4, bundles4, U,
        nxt4, acc4, nullptr, nullptr, 0, n2, 0.5f);
    // L2: res = acc + l2norm(spmm/3); rows<U -> hist_users, rows>=U -> hist_bundles
    spmm_gather4_kernel<false, false, true, false><<<gridFor(tH, BLK), BLK, 0, stream>>>(
        row_ptr, epack, nxt4, nullptr, nullptr, 0,
        nullptr, acc4, (float4*)(out + Ue), (float4*)(out + 2 * Ue + Be), U, n2, 1.0f / 3.0f);
}

// Round 7
// 589.806 us; speedup vs baseline: 8.2627x; 1.1802x over previous
//
#include <hip/hip_runtime.h>

#define FD 64          // feature dim
#define BR 64          // rows per bucket
#define NBMAX 2560     // max bucket count (aff: ceil(150016/64)=2344)
#define CH 8192        // edges per block in count/scatter

// ---------------- utility ----------------

static __global__ void zero_int_kernel(int* __restrict__ p, int n) {
    int i = blockIdx.x * blockDim.x + threadIdx.x;
    if (i < n) p[i] = 0;
}

static inline unsigned gridFor(long long n, int block) {
    return (unsigned)((n + block - 1) / block);
}

static __device__ inline unsigned short f2bf(float x) {
    unsigned u = __float_as_uint(x);
    unsigned r = ((u >> 16) & 1u) + 0x7FFFu;
    return (unsigned short)((u + r) >> 16);
}
static __device__ inline float bf2f(unsigned short h) {
    return __uint_as_float((unsigned)h << 16);
}

// pack f32 quads -> bf16 quads
static __global__ void pack_bf16_kernel(const float4* __restrict__ src,
                                        ushort4* __restrict__ dst, long long nq) {
    long long i = (long long)blockIdx.x * blockDim.x + threadIdx.x;
    if (i >= nq) return;
    float4 f = src[i];
    dst[i] = make_ushort4(f2bf(f.x), f2bf(f.y), f2bf(f.z), f2bf(f.w));
}

// ---------------- bucket build: count -> scan -> clustered scatter -> local sort ----------------

static __global__ void bucket_count_kernel(const int* __restrict__ rows, int nnz, int nb,
                                           int* __restrict__ gcount) {
    __shared__ int h[NBMAX];
    long long c0 = (long long)blockIdx.x * CH;
    int cnt = (int)((nnz - c0) < CH ? (nnz - c0) : CH);
    for (int i = threadIdx.x; i < nb; i += blockDim.x) h[i] = 0;
    __syncthreads();
    for (int i = threadIdx.x; i < cnt; i += blockDim.x)
        atomicAdd(&h[rows[c0 + i] / BR], 1);
    __syncthreads();
    for (int i = threadIdx.x; i < nb; i += blockDim.x)
        if (h[i]) atomicAdd(&gcount[i], h[i]);
}

// single-block exclusive scan of nb (<= NBMAX) counts -> bptr, bcur; bptr[nb] = nnz
static __global__ void bucket_scan_kernel(const int* __restrict__ gcount, int nb, int nnz,
                                          int* __restrict__ bptr, int* __restrict__ bcur) {
    __shared__ int tsum[1024];
    int k = (nb + 1023) / 1024;
    int start = threadIdx.x * k;
    int s = 0;
    for (int i = 0; i < k; ++i) {
        int idx = start + i;
        if (idx < nb) s += gcount[idx];
    }
    tsum[threadIdx.x] = s;
    __syncthreads();
    for (int off = 1; off < 1024; off <<= 1) {
        int t = (threadIdx.x >= (unsigned)off) ? tsum[threadIdx.x - off] : 0;
        __syncthreads();
        tsum[threadIdx.x] += t;
        __syncthreads();
    }
    int run = tsum[threadIdx.x] - s;  // exclusive base for this thread's range
    for (int i = 0; i < k; ++i) {
        int idx = start + i;
        if (idx < nb) {
            bptr[idx] = run;
            bcur[idx] = run;
            run += gcount[idx];
        }
    }
    if (threadIdx.x == 0) bptr[nb] = nnz;
}

// LDS-binned clustered scatter: edges of same bucket from one block land contiguously.
// pack.x = (row % BR) << 24 | col ; pack.y = val bits
static __global__ void bucket_scatter_kernel(const int* __restrict__ rows,
                                             const int* __restrict__ cols,
                                             const float* __restrict__ vals,
                                             int nnz, int nb,
                                             int* __restrict__ bcur,
                                             int2* __restrict__ etmp) {
    __shared__ int h[NBMAX];
    __shared__ int base[NBMAX];
    long long c0 = (long long)blockIdx.x * CH;
    int cnt = (int)((nnz - c0) < CH ? (nnz - c0) : CH);
    for (int i = threadIdx.x; i < nb; i += blockDim.x) h[i] = 0;
    __syncthreads();
    for (int i = threadIdx.x; i < cnt; i += blockDim.x)
        atomicAdd(&h[rows[c0 + i] / BR], 1);
    __syncthreads();
    for (int i = threadIdx.x; i < nb; i += blockDim.x) {
        int c = h[i];
        base[i] = c ? atomicAdd(&bcur[i], c) : 0;
        h[i] = 0;
    }
    __syncthreads();
    for (int i = threadIdx.x; i < cnt; i += blockDim.x) {
        int r = rows[c0 + i];
        int b = r / BR;
        int rank = atomicAdd(&h[b], 1);
        int packed = ((r % BR) << 24) | cols[c0 + i];
        etmp[base[b] + rank] = make_int2(packed, __float_as_int(vals[c0 + i]));
    }
}

// per-bucket counting sort: bucket-sorted etmp -> row-sorted epack (+ row_ptr)
static __global__ void bucket_local_sort_kernel(const int* __restrict__ bptr,
                                                const int2* __restrict__ etmp,
                                                int2* __restrict__ epack,
                                                int* __restrict__ row_ptr,
                                                int n, int nnz) {
    __shared__ int cnt[BR];
    __shared__ int startS[BR];
    int b = blockIdx.x;
    int beg = bptr[b], end = bptr[b + 1];
    if (threadIdx.x < BR) cnt[threadIdx.x] = 0;
    __syncthreads();
    for (int e = beg + threadIdx.x; e < end; e += blockDim.x)
        atomicAdd(&cnt[((unsigned)etmp[e].x) >> 24], 1);
    __syncthreads();
    if (threadIdx.x < BR) {
        int v = cnt[threadIdx.x];
        int s = v;
        #pragma unroll
        for (int off = 1; off < BR; off <<= 1) {
            int t = __shfl_up(s, off);
            if ((int)(threadIdx.x & 63) >= off) s += t;
        }
        startS[threadIdx.x] = s - v;
        cnt[threadIdx.x] = 0;
        int r = b * BR + threadIdx.x;
        if (r < n) row_ptr[r] = beg + s - v;
    }
    __syncthreads();
    for (int e = beg + threadIdx.x; e < end; e += blockDim.x) {
        int2 p = etmp[e];
        int rl = ((unsigned)p.x) >> 24;
        int rank = atomicAdd(&cnt[rl], 1);
        epack[beg + startS[rl] + rank] = make_int2(p.x & 0xFFFFFF, p.y);
    }
    if (b == 0 && threadIdx.x == 0) row_ptr[n] = nnz;
}

static void build_csr(const int* rows, const int* cols, const float* vals,
                      int nnz, int n, int nb,
                      int* gcount, int* bptr, int* bcur, int2* etmp, int2* epack,
                      int* row_ptr, hipStream_t stream) {
    unsigned gb = gridFor(nnz, CH);
    zero_int_kernel<<<gridFor(nb, 256), 256, 0, stream>>>(gcount, nb);
    bucket_count_kernel<<<gb, 256, 0, stream>>>(rows, nnz, nb, gcount);
    bucket_scan_kernel<<<1, 1024, 0, stream>>>(gcount, nb, nnz, bptr, bcur);
    bucket_scatter_kernel<<<gb, 256, 0, stream>>>(rows, cols, vals, nnz, nb, bcur, etmp);
    bucket_local_sort_kernel<<<nb, 256, 0, stream>>>(bptr, etmp, epack, row_ptr, n, nnz);
}

// ---------------- fused gather SpMM over bf16 table, 16 lanes/row x 4 dims ----------------
// Subgroup of 16 lanes per row; lane l holds dims [4l, 4l+4).
// s = scale * sum_e val[e] * bf2f(tab16[col[e]*16 + l])   (f32 accumulate)
// WRITE_NXT16: nxt16[r*16+l] = bf16(s)
// NORM: base = (VIRT_BASE ? (r<split ? fa4 : fb4)[r] : accbuf4[r]); res = base + s/max(||s||,1e-12)
//   WRITE_ACC: accbuf4 = res;  out_lo (r<out_split) / out_hi (r>=out_split) = res
template <bool VIRT_BASE, bool WRITE_NXT16, bool WRITE_ACC>
static __global__ void spmm_gather_bf16_kernel(const int* __restrict__ row_ptr,
                                               const int2* __restrict__ epack,
                                               const ushort4* __restrict__ tab16,
                                               const float4* __restrict__ fa4,
                                               const float4* __restrict__ fb4, int split,
                                               ushort4* __restrict__ nxt16,
                                               float4* __restrict__ accbuf4,
                                               float4* __restrict__ out_lo4,
                                               float4* __restrict__ out_hi4,
                                               int out_split, int n, float scale) {
    long long t = (long long)blockIdx.x * blockDim.x + threadIdx.x;
    int r = (int)(t >> 4);
    if (r >= n) return;
    int l = (int)(t & 15);
    int beg = row_ptr[r];
    int end = row_ptr[r + 1];
    float ax = 0.f, ay = 0.f, az = 0.f, aw = 0.f;
    int e = beg;
    for (; e + 3 < end; e += 4) {
        int2 p0 = epack[e];
        int2 p1 = epack[e + 1];
        int2 p2 = epack[e + 2];
        int2 p3 = epack[e + 3];
        ushort4 h0 = tab16[((long long)p0.x << 4) + l];
        ushort4 h1 = tab16[((long long)p1.x << 4) + l];
        ushort4 h2 = tab16[((long long)p2.x << 4) + l];
        ushort4 h3 = tab16[((long long)p3.x << 4) + l];
        float v0 = __int_as_float(p0.y);
        float v1 = __int_as_float(p1.y);
        float v2 = __int_as_float(p2.y);
        float v3 = __int_as_float(p3.y);
        ax += v0 * bf2f(h0.x); ay += v0 * bf2f(h0.y); az += v0 * bf2f(h0.z); aw += v0 * bf2f(h0.w);
        ax += v1 * bf2f(h1.x); ay += v1 * bf2f(h1.y); az += v1 * bf2f(h1.z); aw += v1 * bf2f(h1.w);
        ax += v2 * bf2f(h2.x); ay += v2 * bf2f(h2.y); az += v2 * bf2f(h2.z); aw += v2 * bf2f(h2.w);
        ax += v3 * bf2f(h3.x); ay += v3 * bf2f(h3.y); az += v3 * bf2f(h3.z); aw += v3 * bf2f(h3.w);
    }
    for (; e < end; ++e) {
        int2 p = epack[e];
        ushort4 h = tab16[((long long)p.x << 4) + l];
        float v = __int_as_float(p.y);
        ax += v * bf2f(h.x); ay += v * bf2f(h.y); az += v * bf2f(h.z); aw += v * bf2f(h.w);
    }
    float4 s;
    s.x = ax * scale; s.y = ay * scale; s.z = az * scale; s.w = aw * scale;
    long long idx = ((long long)r << 4) + l;
    if (WRITE_NXT16) nxt16[idx] = make_ushort4(f2bf(s.x), f2bf(s.y), f2bf(s.z), f2bf(s.w));
    {
        float sq = s.x * s.x + s.y * s.y + s.z * s.z + s.w * s.w;
        #pragma unroll
        for (int off = 8; off > 0; off >>= 1) sq += __shfl_xor(sq, off);
        float inv = 1.0f / fmaxf(sqrtf(sq), 1e-12f);
        float4 basev;
        if (VIRT_BASE)
            basev = (r < split) ? fa4[idx] : fb4[((long long)(r - split) << 4) + l];
        else
            basev = accbuf4[idx];
        float4 res;
        res.x = basev.x + s.x * inv;
        res.y = basev.y + s.y * inv;
        res.z = basev.z + s.z * inv;
        res.w = basev.w + s.w * inv;
        if (WRITE_ACC) accbuf4[idx] = res;
        if (out_lo4 && r < out_split) out_lo4[idx] = res;
        if (out_hi4 && r >= out_split) out_hi4[((long long)(r - out_split) << 4) + l] = res;
    }
}

// ---------------- f32 gather SpMM (agg graph; no norm) ----------------
static __global__ void spmm_gather4_f32_kernel(const int* __restrict__ row_ptr,
                                               const int2* __restrict__ epack,
                                               const float4* __restrict__ feats4,
                                               float4* __restrict__ outbuf4,
                                               int n, float scale) {
    long long t = (long long)blockIdx.x * blockDim.x + threadIdx.x;
    int r = (int)(t >> 4);
    if (r >= n) return;
    int l = (int)(t & 15);
    int beg = row_ptr[r];
    int end = row_ptr[r + 1];
    float4 acc = make_float4(0.f, 0.f, 0.f, 0.f);
    int e = beg;
    for (; e + 1 < end; e += 2) {
        int2 p0 = epack[e];
        int2 p1 = epack[e + 1];
        float4 f0 = feats4[((long long)p0.x << 4) + l];
        float4 f1 = feats4[((long long)p1.x << 4) + l];
        float v0 = __int_as_float(p0.y);
        float v1 = __int_as_float(p1.y);
        acc.x += v0 * f0.x; acc.y += v0 * f0.y; acc.z += v0 * f0.z; acc.w += v0 * f0.w;
        acc.x += v1 * f1.x; acc.y += v1 * f1.y; acc.z += v1 * f1.z; acc.w += v1 * f1.w;
    }
    if (e < end) {
        int2 p = epack[e];
        float4 f = feats4[((long long)p.x << 4) + l];
        float v = __int_as_float(p.y);
        acc.x += v * f.x; acc.y += v * f.y; acc.z += v * f.z; acc.w += v * f.w;
    }
    float4 s;
    s.x = acc.x * scale; s.y = acc.y * scale; s.z = acc.z * scale; s.w = acc.w * scale;
    outbuf4[((long long)r << 4) + l] = s;
}

extern "C" void kernel_launch(void* const* d_in, const int* in_sizes, int n_in,
                              void* d_out, int out_size, void* d_ws, size_t ws_size,
                              hipStream_t stream) {
    const float* users   = (const float*)d_in[0];
    const float* items   = (const float*)d_in[1];
    const float* bundles = (const float*)d_in[2];
    const int*   aff_rows = (const int*)d_in[3];
    const int*   aff_cols = (const int*)d_in[4];
    const float* aff_vals = (const float*)d_in[5];
    const int*   hist_rows = (const int*)d_in[6];
    const int*   hist_cols = (const int*)d_in[7];
    const float* hist_vals = (const float*)d_in[8];
    const int*   agg_rows = (const int*)d_in[9];
    const int*   agg_cols = (const int*)d_in[10];
    const float* agg_vals = (const float*)d_in[11];

    const int U = in_sizes[0] / FD;
    const int I = in_sizes[1] / FD;
    const int B = in_sizes[2] / FD;
    const int nnz_aff  = in_sizes[3];
    const int nnz_hist = in_sizes[6];
    const int nnz_agg  = in_sizes[9];
    const int n1 = U + I;
    const int n2 = U + B;
    int nnz_max = nnz_aff > nnz_hist ? nnz_aff : nnz_hist;
    if (nnz_agg > nnz_max) nnz_max = nnz_agg;

    float* out = (float*)d_out;

    const long long n1e = (long long)n1 * FD;
    const long long Ue  = (long long)U * FD;
    const long long Be  = (long long)B * FD;

    // workspace layout
    float*   acc   = (float*)d_ws;                          // n1e f32
    ushort4* cat16 = (ushort4*)(acc + n1e);                 // n1*16 ushort4 (128 B/row)
    ushort4* nxt16 = cat16 + (long long)n1 * 16;            // n1*16 ushort4
    int2*    etmp  = (int2*)(nxt16 + (long long)n1 * 16);   // nnz_max
    int2*    epack = etmp + nnz_max;                        // nnz_max
    int*     bptr  = (int*)(epack + nnz_max);               // NBMAX+1
    int*     bcur  = bptr + (NBMAX + 1);                    // NBMAX
    int*     gcount = bcur + NBMAX;                         // NBMAX
    int*     row_ptr = gcount + NBMAX;                      // n1+1

    const int BLK = 256;
    const int nbA = (n1 + BR - 1) / BR;
    const int nbH = (n2 + BR - 1) / BR;
    const int nbG = (B + BR - 1) / BR;

    const float4* users4   = (const float4*)users;
    const float4* items4   = (const float4*)items;
    const float4* bundles4 = (const float4*)bundles;
    float4* acc4 = (float4*)acc;
    float4* out4 = (float4*)out;

    // thread counts: 16 threads per row
    const long long tA = (long long)n1 * 16;
    const long long tH = (long long)n2 * 16;
    const long long tG = (long long)B * 16;
    const long long qU = (long long)U * 16;   // quads in users
    const long long qI = (long long)I * 16;
    const long long qB = (long long)B * 16;

    // ---------------- aff propagate over (U+I) nodes ----------------
    build_csr(aff_rows, aff_cols, aff_vals, nnz_aff, n1, nbA,
              gcount, bptr, bcur, etmp, epack, row_ptr, stream);
    pack_bf16_kernel<<<gridFor(qU, BLK), BLK, 0, stream>>>(users4, cat16, qU);
    pack_bf16_kernel<<<gridFor(qI, BLK), BLK, 0, stream>>>(items4, cat16 + qU, qI);
    // L1: s = spmm(cat16)/2 ; nxt16 = bf16(s) ; acc = f32concat + l2norm(s)
    spmm_gather_bf16_kernel<true, true, true><<<gridFor(tA, BLK), BLK, 0, stream>>>(
        row_ptr, epack, cat16, users4, items4, U,
        nxt16, acc4, nullptr, nullptr, 0, n1, 0.5f);
    // L2: acc += l2norm(spmm(nxt16)/3); rows<U also -> out (aff_users)
    spmm_gather_bf16_kernel<false, false, true><<<gridFor(tA, BLK), BLK, 0, stream>>>(
        row_ptr, epack, nxt16, nullptr, nullptr, 0,
        nullptr, acc4, out4, nullptr, U, n1, 1.0f / 3.0f);

    // ---------------- aff_bundles = agg_spmm(aff items, f32) -> out[2U : 2U+B] ----------------
    build_csr(agg_rows, agg_cols, agg_vals, nnz_agg, B, nbG,
              gcount, bptr, bcur, etmp, epack, row_ptr, stream);
    spmm_gather4_f32_kernel<<<gridFor(tG, BLK), BLK, 0, stream>>>(
        row_ptr, epack, (const float4*)(acc + Ue), (float4*)(out + 2 * Ue), B, 1.0f);

    // ---------------- hist propagate over (U+B) nodes ----------------
    build_csr(hist_rows, hist_cols, hist_vals, nnz_hist, n2, nbH,
              gcount, bptr, bcur, etmp, epack, row_ptr, stream);
    pack_bf16_kernel<<<gridFor(qU, BLK), BLK, 0, stream>>>(users4, cat16, qU);
    pack_bf16_kernel<<<gridFor(qB, BLK), BLK, 0, stream>>>(bundles4, cat16 + qU, qB);
    spmm_gather_bf16_kernel<true, true, true><<<gridFor(tH, BLK), BLK, 0, stream>>>(
        row_ptr, epack, cat16, users4, bundles4, U,
        nxt16, acc4, nullptr, nullptr, 0, n2, 0.5f);
    // L2: res = acc + l2norm(spmm/3); rows<U -> hist_users, rows>=U -> hist_bundles
    spmm_gather_bf16_kernel<false, false, false><<<gridFor(tH, BLK), BLK, 0, stream>>>(
        row_ptr, epack, nxt16, nullptr, nullptr, 0,
        nullptr, acc4, (float4*)(out + Ue), (float4*)(out + 2 * Ue + Be), U, n2, 1.0f / 3.0f);
}